// Round 4
// baseline (443.159 us; speedup 1.0000x reference)
//
#include <hip/hip_runtime.h>
#include <math.h>

#define B_ 8
#define S_ 1024
#define E_ 768
#define H_ 12
#define P_ 64

typedef __attribute__((ext_vector_type(8))) short bf16x8;
typedef __attribute__((ext_vector_type(4))) float f32x4;

__device__ __forceinline__ short f2bf(float f) {        // RNE
    union { float f; unsigned u; } v; v.f = f;
    unsigned r = v.u + 0x7FFFu + ((v.u >> 16) & 1u);
    return (short)(r >> 16);
}
__device__ __forceinline__ short f2bf_hu(float f) {     // round-half-away (cheap)
    union { float f; unsigned u; } v; v.f = f;
    return (short)((v.u + 0x8000u) >> 16);
}

// ---------------------------------------------------------------------------
// fp32 -> bf16 straight conversion (n multiple of 1024)
// ---------------------------------------------------------------------------
__global__ __launch_bounds__(256) void conv_bf16_kernel(
    const float4* __restrict__ src, ushort4* __restrict__ dst)
{
    int idx = blockIdx.x * 256 + threadIdx.x;
    float4 f = src[idx];
    ushort4 u;
    u.x = (unsigned short)f2bf(f.x);
    u.y = (unsigned short)f2bf(f.y);
    u.z = (unsigned short)f2bf(f.z);
    u.w = (unsigned short)f2bf(f.w);
    dst[idx] = u;
}

// ---------------------------------------------------------------------------
// fp32 [batch][R][C] -> bf16 [batch][C][R] transpose. grid (R/64, C/64, batch)
// ---------------------------------------------------------------------------
__global__ __launch_bounds__(256) void conv_T_kernel(
    const float* __restrict__ src0, short* __restrict__ dst0, int R, int C)
{
    __shared__ short T[64][72];
    const int t = threadIdx.x;
    const int r0 = blockIdx.x * 64, c0 = blockIdx.y * 64;
    const size_t bo = (size_t)blockIdx.z * R * C;
    const float* src = src0 + bo;
    short* dst = dst0 + bo;
#pragma unroll
    for (int i = 0; i < 4; ++i) {
        int id = i * 256 + t;
        int r = id >> 4, c4 = id & 15;
        float4 f = *(const float4*)(src + (size_t)(r0 + r) * C + c0 + c4 * 4);
        T[c4 * 4 + 0][r] = f2bf(f.x);
        T[c4 * 4 + 1][r] = f2bf(f.y);
        T[c4 * 4 + 2][r] = f2bf(f.z);
        T[c4 * 4 + 3][r] = f2bf(f.w);
    }
    __syncthreads();
#pragma unroll
    for (int i = 0; i < 2; ++i) {
        int id = i * 256 + t;
        int cc = id >> 3, r8 = id & 7;
        *(uint4*)(dst + (size_t)(c0 + cc) * R + r0 + r8 * 8) = *(const uint4*)&T[cc][r8 * 8];
    }
}

// ---------------------------------------------------------------------------
// 128x128 MFMA GEMM core, 4 waves in 2x2 quadrants, BK=64, register-prefetch
// double buffer. A row-major (lda), Bt row-major (ldb). K % 64 == 0.
// Shared memory passed in as one 18432-short buffer (As | Bs); the epilogue
// reuses it as a [128][132] staging tile (16896 shorts) after a barrier.
// ---------------------------------------------------------------------------
__device__ __forceinline__ void mfma_gemm_128x128(
    const short* __restrict__ A, int lda,
    const short* __restrict__ Bt, int ldb, int K,
    short* smem, f32x4 (&acc)[4][4])
{
    short (*As)[72] = (short(*)[72])smem;
    short (*Bs)[72] = (short(*)[72])(smem + 128 * 72);
    const int tid = threadIdx.x;
    const int w = tid >> 6, lane = tid & 63, quad = lane >> 4, ln = lane & 15;
    const int wr = (w >> 1) * 64, wc = (w & 1) * 64;
    const int r_st = tid >> 3, c8 = tid & 7;

    uint4 pa[4], pb[4];
#pragma unroll
    for (int i = 0; i < 4; ++i) {
        pa[i] = *(const uint4*)(A + (size_t)(r_st + 32 * i) * lda + c8 * 8);
        pb[i] = *(const uint4*)(Bt + (size_t)(r_st + 32 * i) * ldb + c8 * 8);
    }
    for (int k0 = 0; k0 < K; k0 += 64) {
        __syncthreads();
#pragma unroll
        for (int i = 0; i < 4; ++i) {
            *(uint4*)&As[r_st + 32 * i][c8 * 8] = pa[i];
            *(uint4*)&Bs[r_st + 32 * i][c8 * 8] = pb[i];
        }
        __syncthreads();
        if (k0 + 64 < K) {
#pragma unroll
            for (int i = 0; i < 4; ++i) {
                pa[i] = *(const uint4*)(A + (size_t)(r_st + 32 * i) * lda + k0 + 64 + c8 * 8);
                pb[i] = *(const uint4*)(Bt + (size_t)(r_st + 32 * i) * ldb + k0 + 64 + c8 * 8);
            }
        }
#pragma unroll
        for (int kc = 0; kc < 2; ++kc) {
            bf16x8 af[4], bfr[4];
#pragma unroll
            for (int mi = 0; mi < 4; ++mi)
                af[mi] = *(const bf16x8*)&As[wr + mi * 16 + ln][kc * 32 + quad * 8];
#pragma unroll
            for (int ni = 0; ni < 4; ++ni)
                bfr[ni] = *(const bf16x8*)&Bs[wc + ni * 16 + ln][kc * 32 + quad * 8];
#pragma unroll
            for (int mi = 0; mi < 4; ++mi)
#pragma unroll
                for (int ni = 0; ni < 4; ++ni)
                    acc[mi][ni] = __builtin_amdgcn_mfma_f32_16x16x32_bf16(
                        af[mi], bfr[ni], acc[mi][ni], 0, 0, 0);
        }
    }
}

// Write one staged row-segment: 128 B from Epi[row][half*64..+63] to dst.
__device__ __forceinline__ void epi_row_out(const short (*Epi)[132], int row,
                                            int half, short* dst)
{
#pragma unroll
    for (int c = 0; c < 8; ++c) {
        uint2 a = *(const uint2*)&Epi[row][half * 64 + c * 8];
        uint2 b = *(const uint2*)&Epi[row][half * 64 + c * 8 + 4];
        uint4 v = make_uint4(a.x, a.y, b.x, b.y);
        *(uint4*)(dst + c * 8) = v;
    }
}

// ---------------------------------------------------------------------------
// Stage 1 (fused over heads): k = x @ Wk (8192x768x768), v likewise.
// z=0 -> kb [b,h,s,p]; z=1 -> vTb [b,h,p,s]. grid (64, 6, 2).
// Epilogues staged through LDS for fully-coalesced 128B-per-thread stores.
// ---------------------------------------------------------------------------
__global__ __launch_bounds__(256) void proj_mfma(
    const short* __restrict__ xb,
    const short* __restrict__ kTw,   // [(h*64+p)][e] = Bt (768x768)
    const short* __restrict__ vTw,
    short* __restrict__ kb,
    short* __restrict__ vTb)
{
    __shared__ short smem[128 * 72 * 2];
    const int tid = threadIdx.x;
    const int w = tid >> 6, lane = tid & 63, quad = lane >> 4, ln = lane & 15;
    const int wr = (w >> 1) * 64, wc = (w & 1) * 64;
    const int m0 = blockIdx.x * 128, n0 = blockIdx.y * 128;
    const int z = blockIdx.z;

    const short* Bt = (z ? vTw : kTw) + (size_t)n0 * E_;
    f32x4 acc[4][4] = {};
    mfma_gemm_128x128(xb + (size_t)m0 * E_, E_, Bt, E_, E_, smem, acc);

    const int b = m0 >> 10, sb = m0 & 1023;
    short (*Epi)[132] = (short(*)[132])smem;
    __syncthreads();   // all MFMA reads of As/Bs complete before reuse

    if (z == 0) {
        // stage row-major: Epi[s_local][n_local]
#pragma unroll
        for (int mi = 0; mi < 4; ++mi)
#pragma unroll
            for (int ni = 0; ni < 4; ++ni)
#pragma unroll
                for (int r = 0; r < 4; ++r)
                    Epi[wr + mi * 16 + quad * 4 + r][wc + ni * 16 + ln] =
                        f2bf_hu(acc[mi][ni][r]);
        __syncthreads();
        int s_loc = tid & 127, half = tid >> 7;
        int h = (n0 >> 6) + half;
        short* dst = kb + ((size_t)(b * H_ + h) * S_ + sb + s_loc) * P_;
        epi_row_out(Epi, s_loc, half, dst);
    } else {
        // stage transposed: Epi[n_local][s_local], r packed as ushort4
#pragma unroll
        for (int mi = 0; mi < 4; ++mi)
#pragma unroll
            for (int ni = 0; ni < 4; ++ni) {
                ushort4 u;
                u.x = (unsigned short)f2bf_hu(acc[mi][ni][0]);
                u.y = (unsigned short)f2bf_hu(acc[mi][ni][1]);
                u.z = (unsigned short)f2bf_hu(acc[mi][ni][2]);
                u.w = (unsigned short)f2bf_hu(acc[mi][ni][3]);
                *(ushort4*)&Epi[wc + ni * 16 + ln][wr + mi * 16 + quad * 4] = u;
            }
        __syncthreads();
        int c_loc = tid & 127, half = tid >> 7;
        int h = (n0 >> 6) + (c_loc >> 6), p = c_loc & 63;
        short* dst = vTb + ((size_t)(b * H_ + h) * P_ + p) * S_ + sb + half * 64;
        epi_row_out(Epi, c_loc, half, dst);
    }
}

// ---------------------------------------------------------------------------
// Stage 2: qv[b,h] = q_heads[h] @ v[b,h]; two batches per block (N=128).
// Scale*log2e folded in. LDS-staged epilogue. grid (8, 12, 4).
// ---------------------------------------------------------------------------
__global__ __launch_bounds__(256) void qv_mfma(
    const short* __restrict__ qhb,
    const short* __restrict__ vTb,
    short* __restrict__ qvb)
{
    __shared__ short smem[128 * 72 * 2];
    short (*As)[72] = (short(*)[72])smem;
    short (*Bs)[72] = (short(*)[72])(smem + 128 * 72);
    const int tid = threadIdx.x;
    const int w = tid >> 6, lane = tid & 63, quad = lane >> 4, ln = lane & 15;
    const int wr = (w >> 1) * 64, wc = (w & 1) * 64;
    const int m0 = blockIdx.x * 128;
    const int h = blockIdx.y;
    const int b1 = blockIdx.z * 2, b2 = b1 + 1;
    const int r_st = tid >> 3, c8 = tid & 7;

    const short* A   = qhb + (size_t)h * S_ * S_ + (size_t)m0 * S_;
    const short* Bt1 = vTb + (size_t)(b1 * H_ + h) * P_ * S_;
    const short* Bt2 = vTb + (size_t)(b2 * H_ + h) * P_ * S_;
    const short* Arow[4] = { A + (size_t)r_st * S_, A + (size_t)(r_st + 32) * S_,
                             A + (size_t)(r_st + 64) * S_, A + (size_t)(r_st + 96) * S_ };
    const short* Brow[4] = { Bt1 + (size_t)r_st * S_, Bt1 + (size_t)(r_st + 32) * S_,
                             Bt2 + (size_t)r_st * S_, Bt2 + (size_t)(r_st + 32) * S_ };

    f32x4 acc[4][4] = {};
    uint4 pa[4], pb[4];
#pragma unroll
    for (int i = 0; i < 4; ++i) {
        pa[i] = *(const uint4*)(Arow[i] + c8 * 8);
        pb[i] = *(const uint4*)(Brow[i] + c8 * 8);
    }
    for (int k0 = 0; k0 < S_; k0 += 64) {
        __syncthreads();
#pragma unroll
        for (int i = 0; i < 4; ++i) {
            *(uint4*)&As[r_st + 32 * i][c8 * 8] = pa[i];
            *(uint4*)&Bs[r_st + 32 * i][c8 * 8] = pb[i];
        }
        __syncthreads();
        if (k0 + 64 < S_) {
#pragma unroll
            for (int i = 0; i < 4; ++i) {
                pa[i] = *(const uint4*)(Arow[i] + k0 + 64 + c8 * 8);
                pb[i] = *(const uint4*)(Brow[i] + k0 + 64 + c8 * 8);
            }
        }
#pragma unroll
        for (int kc = 0; kc < 2; ++kc) {
            bf16x8 af[4], bfr[4];
#pragma unroll
            for (int mi = 0; mi < 4; ++mi)
                af[mi] = *(const bf16x8*)&As[wr + mi * 16 + ln][kc * 32 + quad * 8];
#pragma unroll
            for (int ni = 0; ni < 4; ++ni)
                bfr[ni] = *(const bf16x8*)&Bs[wc + ni * 16 + ln][kc * 32 + quad * 8];
#pragma unroll
            for (int mi = 0; mi < 4; ++mi)
#pragma unroll
                for (int ni = 0; ni < 4; ++ni)
                    acc[mi][ni] = __builtin_amdgcn_mfma_f32_16x16x32_bf16(
                        af[mi], bfr[ni], acc[mi][ni], 0, 0, 0);
        }
    }

    const float cs = 0.03608439182435161f * 1.4426950408889634f;  // 1/sqrt(E)*log2e
    short (*Epi)[132] = (short(*)[132])smem;
    __syncthreads();
#pragma unroll
    for (int mi = 0; mi < 4; ++mi)
#pragma unroll
        for (int ni = 0; ni < 4; ++ni)
#pragma unroll
            for (int r = 0; r < 4; ++r)
                Epi[wr + mi * 16 + quad * 4 + r][wc + ni * 16 + ln] =
                    f2bf_hu(acc[mi][ni][r] * cs);
    __syncthreads();
    int s_loc = tid & 127, half = tid >> 7;
    int bb = half ? b2 : b1;
    short* dst = qvb + ((size_t)(bb * H_ + h) * S_ + m0 + s_loc) * P_;
    epi_row_out(Epi, s_loc, half, dst);
}

// ---------------------------------------------------------------------------
// Stage 3: flash attention, fixed-max softmax (P = exp2(s), scale*log2e folded
// into qvb). Paired q-tiles (qbA=bx, qbB=15-bx): every block 17 tile-steps.
// K/V reg-prefetch; P wave-private. grid (8, 96).
// ---------------------------------------------------------------------------
__device__ __forceinline__ void flash_step(
    const bf16x8 (&qf)[2], bool diag, int w, int quad, int ln,
    short (*Ks)[72], short (*Vts)[72], short (*Ps)[72],
    f32x4 (&o)[4], float (&lsum)[4])
{
    f32x4 s[4] = {};
#pragma unroll
    for (int kc = 0; kc < 2; ++kc)
#pragma unroll
        for (int ni = 0; ni < 4; ++ni) {
            bf16x8 kf = *(const bf16x8*)&Ks[ni * 16 + ln][kc * 32 + quad * 8];
            s[ni] = __builtin_amdgcn_mfma_f32_16x16x32_bf16(qf[kc], kf, s[ni], 0, 0, 0);
        }
#pragma unroll
    for (int ni = 0; ni < 4; ++ni)
#pragma unroll
        for (int r = 0; r < 4; ++r) {
            bool msk = diag && (ni * 16 + ln) > (w * 16 + quad * 4 + r);
            float p = msk ? 0.f : __builtin_amdgcn_exp2f(s[ni][r]);
            lsum[r] += p;
            Ps[w * 16 + quad * 4 + r][ni * 16 + ln] = f2bf_hu(p);
        }
    // same-wave DS ordering: P writes land before these reads
#pragma unroll
    for (int kc = 0; kc < 2; ++kc) {
        bf16x8 pa = *(const bf16x8*)&Ps[w * 16 + ln][kc * 32 + quad * 8];
#pragma unroll
        for (int ni = 0; ni < 4; ++ni) {
            bf16x8 vb = *(const bf16x8*)&Vts[ni * 16 + ln][kc * 32 + quad * 8];
            o[ni] = __builtin_amdgcn_mfma_f32_16x16x32_bf16(pa, vb, o[ni], 0, 0, 0);
        }
    }
}

__global__ __launch_bounds__(256) void flash_mfma(
    const short* __restrict__ kb,
    const short* __restrict__ qvb,
    const short* __restrict__ vTb,
    short* __restrict__ attn2)
{
    __shared__ short Ks[64][72];
    __shared__ short Vts[64][72];
    __shared__ short Ps[64][72];

    const int tid = threadIdx.x;
    const int w = tid >> 6, lane = tid & 63, quad = lane >> 4, ln = lane & 15;
    const int qbA = blockIdx.x;          // 0..7
    const int qbB = 15 - qbA;            // 8..15
    const int bh = blockIdx.y;
    const int b = bh / H_, h = bh % H_;

    const short* Q  = kb  + (size_t)bh * S_ * P_;
    const short* K  = qvb + (size_t)bh * S_ * P_;
    const short* Vt = vTb + (size_t)bh * P_ * S_;

    bf16x8 qfA[2], qfB[2];
    {
        const short* qa = Q + (size_t)(qbA * 64 + w * 16 + ln) * P_ + quad * 8;
        const short* qc = Q + (size_t)(qbB * 64 + w * 16 + ln) * P_ + quad * 8;
        qfA[0] = *(const bf16x8*)(qa);
        qfA[1] = *(const bf16x8*)(qa + 32);
        qfB[0] = *(const bf16x8*)(qc);
        qfB[1] = *(const bf16x8*)(qc + 32);
    }

    f32x4 oA[4] = {}, oB[4] = {};
    float lA[4] = {}, lB[4] = {};

    const int r_st = tid >> 3, c8 = tid & 7;
    uint4 pk[2], pv[2];
#pragma unroll
    for (int i = 0; i < 2; ++i) {
        pk[i] = *(const uint4*)(K + (size_t)(r_st + 32 * i) * P_ + c8 * 8);
        pv[i] = *(const uint4*)(Vt + (size_t)(r_st + 32 * i) * S_ + c8 * 8);
    }

    for (int jt = 0; jt <= qbB; ++jt) {
        __syncthreads();
#pragma unroll
        for (int i = 0; i < 2; ++i) {
            *(uint4*)&Ks[r_st + 32 * i][c8 * 8]  = pk[i];
            *(uint4*)&Vts[r_st + 32 * i][c8 * 8] = pv[i];
        }
        __syncthreads();
        if (jt < qbB) {
            int jn = jt + 1;
#pragma unroll
            for (int i = 0; i < 2; ++i) {
                pk[i] = *(const uint4*)(K + (size_t)(jn * 64 + r_st + 32 * i) * P_ + c8 * 8);
                pv[i] = *(const uint4*)(Vt + (size_t)(r_st + 32 * i) * S_ + jn * 64 + c8 * 8);
            }
        }
        flash_step(qfB, jt == qbB, w, quad, ln, Ks, Vts, Ps, oB, lB);
        if (jt <= qbA)
            flash_step(qfA, jt == qbA, w, quad, ln, Ks, Vts, Ps, oA, lA);
    }

#pragma unroll
    for (int r = 0; r < 4; ++r) {
#pragma unroll
        for (int off = 1; off < 16; off <<= 1) {
            lA[r] += __shfl_xor(lA[r], off, 16);
            lB[r] += __shfl_xor(lB[r], off, 16);
        }
    }

    const size_t HP = H_ * P_;
#pragma unroll
    for (int r = 0; r < 4; ++r) {
        float invA = 1.0f / lA[r], invB = 1.0f / lB[r];
        int giA = qbA * 64 + w * 16 + quad * 4 + r;
        int giB = qbB * 64 + w * 16 + quad * 4 + r;
#pragma unroll
        for (int ni = 0; ni < 4; ++ni) {
            attn2[((size_t)b * S_ + giA) * HP + h * P_ + ni * 16 + ln] = f2bf_hu(oA[ni][r] * invA);
            attn2[((size_t)b * S_ + giB) * HP + h * P_ + ni * 16 + ln] = f2bf_hu(oB[ni][r] * invB);
        }
    }
}

// ---------------------------------------------------------------------------
// Stage 4: out(8192x768) = attn2 @ lifting (fp32 out, 64B/quad lines — no
// staging needed). grid (64, 6).
// ---------------------------------------------------------------------------
__global__ __launch_bounds__(256) void lift_mfma(
    const short* __restrict__ attn2,
    const short* __restrict__ liftT,
    float* __restrict__ outp)
{
    __shared__ short smem[128 * 72 * 2];
    const int tid = threadIdx.x;
    const int w = tid >> 6, lane = tid & 63, quad = lane >> 4, ln = lane & 15;
    const int wr = (w >> 1) * 64, wc = (w & 1) * 64;
    const int m0 = blockIdx.x * 128, n0 = blockIdx.y * 128;

    f32x4 acc[4][4] = {};
    mfma_gemm_128x128(attn2 + (size_t)m0 * E_, E_,
                      liftT + (size_t)n0 * E_, E_, E_, smem, acc);

#pragma unroll
    for (int mi = 0; mi < 4; ++mi)
#pragma unroll
        for (int ni = 0; ni < 4; ++ni)
#pragma unroll
            for (int r = 0; r < 4; ++r) {
                int m = m0 + wr + mi * 16 + quad * 4 + r;
                int n = n0 + wc + ni * 16 + ln;
                outp[(size_t)m * E_ + n] = acc[mi][ni][r];
            }
}

extern "C" void kernel_launch(void* const* d_in, const int* in_sizes, int n_in,
                              void* d_out, int out_size, void* d_ws, size_t ws_size,
                              hipStream_t stream) {
    (void)in_sizes; (void)n_in; (void)out_size; (void)ws_size;
    const float* x       = (const float*)d_in[0];
    const float* kproj   = (const float*)d_in[1];
    const float* vproj   = (const float*)d_in[2];
    const float* qheads  = (const float*)d_in[3];
    const float* lifting = (const float*)d_in[4];
    float* out = (float*)d_out;

    short* ws = (short*)d_ws;
    const size_t N_X  = (size_t)B_ * S_ * E_;
    const size_t N_QH = (size_t)H_ * S_ * S_;
    const size_t N_W  = (size_t)H_ * P_ * E_;
    const size_t N_L  = (size_t)E_ * E_;
    const size_t N_KV = (size_t)B_ * H_ * S_ * P_;

    short* xb    = ws;  ws += N_X;
    short* qhb   = ws;  ws += N_QH;
    short* kTw   = ws;  ws += N_W;
    short* vTw   = ws;  ws += N_W;
    short* liftT = ws;  ws += N_L;
    short* kb    = ws;  ws += N_KV;
    short* vTb   = ws;  ws += N_KV;
    short* qvb   = ws;  ws += N_KV;
    short* attn2 = ws;  ws += N_KV;

    conv_bf16_kernel<<<(int)(N_X / 1024), 256, 0, stream>>>((const float4*)x, (ushort4*)xb);
    conv_bf16_kernel<<<(int)(N_QH / 1024), 256, 0, stream>>>((const float4*)qheads, (ushort4*)qhb);
    conv_T_kernel<<<dim3(E_ / 64, P_ / 64, H_), 256, 0, stream>>>(kproj, kTw, E_, P_);
    conv_T_kernel<<<dim3(E_ / 64, P_ / 64, H_), 256, 0, stream>>>(vproj, vTw, E_, P_);
    conv_T_kernel<<<dim3(E_ / 64, E_ / 64, 1), 256, 0, stream>>>(lifting, liftT, E_, E_);

    proj_mfma<<<dim3((B_ * S_) / 128, E_ / 128, 2), 256, 0, stream>>>(xb, kTw, vTw, kb, vTb);
    qv_mfma<<<dim3(S_ / 128, H_, B_ / 2), 256, 0, stream>>>(qhb, vTb, qvb);
    flash_mfma<<<dim3(8, B_ * H_), 256, 0, stream>>>(kb, qvb, vTb, attn2);
    lift_mfma<<<dim3((B_ * S_) / 128, E_ / 128), 256, 0, stream>>>(attn2, liftT, out);
}

// Round 5
// 387.938 us; speedup vs baseline: 1.1423x; 1.1423x over previous
//
#include <hip/hip_runtime.h>
#include <math.h>

#define B_ 8
#define S_ 1024
#define E_ 768
#define H_ 12
#define P_ 64

typedef __attribute__((ext_vector_type(8))) short bf16x8;
typedef __attribute__((ext_vector_type(4))) float f32x4;

__device__ __forceinline__ short f2bf(float f) {        // RNE
    union { float f; unsigned u; } v; v.f = f;
    unsigned r = v.u + 0x7FFFu + ((v.u >> 16) & 1u);
    return (short)(r >> 16);
}
__device__ __forceinline__ short f2bf_hu(float f) {     // round-half-away (cheap)
    union { float f; unsigned u; } v; v.f = f;
    return (short)((v.u + 0x8000u) >> 16);
}
__device__ __forceinline__ unsigned bfu(float f) {
    union { float f; unsigned u; } v; v.f = f;
    return (v.u + 0x8000u) >> 16;
}
// pack 8 fp32 -> 8 bf16 in a uint4 (half-away rounding)
__device__ __forceinline__ uint4 pack8(float4 a, float4 b) {
    uint4 r;
    r.x = bfu(a.x) | (bfu(a.y) << 16);
    r.y = bfu(a.z) | (bfu(a.w) << 16);
    r.z = bfu(b.x) | (bfu(b.y) << 16);
    r.w = bfu(b.z) | (bfu(b.w) << 16);
    return r;
}

// ---------------------------------------------------------------------------
// fp32 [batch][R][C] -> bf16 [batch][C][R] transpose (weights only — tiny).
// grid (R/64, C/64, batch)
// ---------------------------------------------------------------------------
__global__ __launch_bounds__(256) void conv_T_kernel(
    const float* __restrict__ src0, short* __restrict__ dst0, int R, int C)
{
    __shared__ short T[64][72];
    const int t = threadIdx.x;
    const int r0 = blockIdx.x * 64, c0 = blockIdx.y * 64;
    const size_t bo = (size_t)blockIdx.z * R * C;
    const float* src = src0 + bo;
    short* dst = dst0 + bo;
#pragma unroll
    for (int i = 0; i < 4; ++i) {
        int id = i * 256 + t;
        int r = id >> 4, c4 = id & 15;
        float4 f = *(const float4*)(src + (size_t)(r0 + r) * C + c0 + c4 * 4);
        T[c4 * 4 + 0][r] = f2bf(f.x);
        T[c4 * 4 + 1][r] = f2bf(f.y);
        T[c4 * 4 + 2][r] = f2bf(f.z);
        T[c4 * 4 + 3][r] = f2bf(f.w);
    }
    __syncthreads();
#pragma unroll
    for (int i = 0; i < 2; ++i) {
        int id = i * 256 + t;
        int cc = id >> 3, r8 = id & 7;
        *(uint4*)(dst + (size_t)(c0 + cc) * R + r0 + r8 * 8) = *(const uint4*)&T[cc][r8 * 8];
    }
}

// Write staged 128B row-segment from Epi[row][half*64..+63] to dst.
__device__ __forceinline__ void epi_row_out(const short (*Epi)[132], int row,
                                            int half, short* dst)
{
#pragma unroll
    for (int c = 0; c < 8; ++c) {
        uint2 a = *(const uint2*)&Epi[row][half * 64 + c * 8];
        uint2 b = *(const uint2*)&Epi[row][half * 64 + c * 8 + 4];
        *(uint4*)(dst + c * 8) = make_uint4(a.x, a.y, b.x, b.y);
    }
}

// ---------------------------------------------------------------------------
// Stage 1: k = x @ Wk, v = x @ Wv (x read fp32, converted in-register).
// 128x128 tiles, 4 waves 2x2 quadrants, BK=64, reg-prefetch.
// z=0 -> kb [b,h,s,p]; z=1 -> vTb [b,h,p,s]. grid (64, 6, 2) = 768 blocks.
// ---------------------------------------------------------------------------
__global__ __launch_bounds__(256) void proj_mfma(
    const float* __restrict__ x,
    const short* __restrict__ kTw,   // [(h*64+p)][e]
    const short* __restrict__ vTw,
    short* __restrict__ kb,
    short* __restrict__ vTb)
{
    __shared__ short smem[128 * 72 * 2];
    short (*As)[72] = (short(*)[72])smem;
    short (*Bs)[72] = (short(*)[72])(smem + 128 * 72);
    const int tid = threadIdx.x;
    const int w = tid >> 6, lane = tid & 63, quad = lane >> 4, ln = lane & 15;
    const int wr = (w >> 1) * 64, wc = (w & 1) * 64;
    const int m0 = blockIdx.x * 128, n0 = blockIdx.y * 128;
    const int z = blockIdx.z;
    const int r_st = tid >> 3, c8 = tid & 7;

    const float* A  = x + (size_t)m0 * E_;
    const short* Bt = (z ? vTw : kTw) + (size_t)n0 * E_;

    float4 paf[4][2];
    uint4 pb[4];
#pragma unroll
    for (int i = 0; i < 4; ++i) {
        const float* ap = A + (size_t)(r_st + 32 * i) * E_ + c8 * 8;
        paf[i][0] = *(const float4*)ap;
        paf[i][1] = *(const float4*)(ap + 4);
        pb[i] = *(const uint4*)(Bt + (size_t)(r_st + 32 * i) * E_ + c8 * 8);
    }
    f32x4 acc[4][4] = {};
    for (int k0 = 0; k0 < E_; k0 += 64) {
        __syncthreads();
#pragma unroll
        for (int i = 0; i < 4; ++i) {
            *(uint4*)&As[r_st + 32 * i][c8 * 8] = pack8(paf[i][0], paf[i][1]);
            *(uint4*)&Bs[r_st + 32 * i][c8 * 8] = pb[i];
        }
        __syncthreads();
        if (k0 + 64 < E_) {
#pragma unroll
            for (int i = 0; i < 4; ++i) {
                const float* ap = A + (size_t)(r_st + 32 * i) * E_ + k0 + 64 + c8 * 8;
                paf[i][0] = *(const float4*)ap;
                paf[i][1] = *(const float4*)(ap + 4);
                pb[i] = *(const uint4*)(Bt + (size_t)(r_st + 32 * i) * E_ + k0 + 64 + c8 * 8);
            }
        }
#pragma unroll
        for (int kc = 0; kc < 2; ++kc) {
            bf16x8 af[4], bfr[4];
#pragma unroll
            for (int mi = 0; mi < 4; ++mi)
                af[mi] = *(const bf16x8*)&As[wr + mi * 16 + ln][kc * 32 + quad * 8];
#pragma unroll
            for (int ni = 0; ni < 4; ++ni)
                bfr[ni] = *(const bf16x8*)&Bs[wc + ni * 16 + ln][kc * 32 + quad * 8];
#pragma unroll
            for (int mi = 0; mi < 4; ++mi)
#pragma unroll
                for (int ni = 0; ni < 4; ++ni)
                    acc[mi][ni] = __builtin_amdgcn_mfma_f32_16x16x32_bf16(
                        af[mi], bfr[ni], acc[mi][ni], 0, 0, 0);
        }
    }

    const int b = m0 >> 10, sb = m0 & 1023;
    short (*Epi)[132] = (short(*)[132])smem;
    __syncthreads();
    if (z == 0) {
#pragma unroll
        for (int mi = 0; mi < 4; ++mi)
#pragma unroll
            for (int ni = 0; ni < 4; ++ni)
#pragma unroll
                for (int r = 0; r < 4; ++r)
                    Epi[wr + mi * 16 + quad * 4 + r][wc + ni * 16 + ln] =
                        f2bf_hu(acc[mi][ni][r]);
        __syncthreads();
        int s_loc = tid & 127, half = tid >> 7;
        int h = (n0 >> 6) + half;
        short* dst = kb + ((size_t)(b * H_ + h) * S_ + sb + s_loc) * P_;
        epi_row_out(Epi, s_loc, half, dst);
    } else {
#pragma unroll
        for (int mi = 0; mi < 4; ++mi)
#pragma unroll
            for (int ni = 0; ni < 4; ++ni) {
                ushort4 u;
                u.x = (unsigned short)f2bf_hu(acc[mi][ni][0]);
                u.y = (unsigned short)f2bf_hu(acc[mi][ni][1]);
                u.z = (unsigned short)f2bf_hu(acc[mi][ni][2]);
                u.w = (unsigned short)f2bf_hu(acc[mi][ni][3]);
                *(ushort4*)&Epi[wc + ni * 16 + ln][wr + mi * 16 + quad * 4] = u;
            }
        __syncthreads();
        int c_loc = tid & 127, half = tid >> 7;
        int h = (n0 >> 6) + (c_loc >> 6), p = c_loc & 63;
        short* dst = vTb + ((size_t)(b * H_ + h) * P_ + p) * S_ + sb + half * 64;
        epi_row_out(Epi, c_loc, half, dst);
    }
}

// ---------------------------------------------------------------------------
// Stage 2: qv[b,h] = q_heads[h] @ v[b,h] (q_heads read fp32, converted
// in-register). 128x64 tiles, 768 blocks: grid (8, 12, 8). Scale*log2e folded.
// ---------------------------------------------------------------------------
__global__ __launch_bounds__(256) void qv_mfma(
    const float* __restrict__ qh,
    const short* __restrict__ vTb,
    short* __restrict__ qvb)
{
    __shared__ short smem[128 * 72 + 64 * 72];
    short (*As)[72] = (short(*)[72])smem;
    short (*Bs)[72] = (short(*)[72])(smem + 128 * 72);
    const int tid = threadIdx.x;
    const int w = tid >> 6, lane = tid & 63, quad = lane >> 4, ln = lane & 15;
    const int m0 = blockIdx.x * 128;
    const int h = blockIdx.y, b = blockIdx.z;
    const int r_st = tid >> 3, c8 = tid & 7;

    const float* A  = qh + (size_t)h * S_ * S_ + (size_t)m0 * S_;
    const short* Bt = vTb + (size_t)(b * H_ + h) * P_ * S_;

    float4 paf[4][2];
    uint4 pb[2];
#pragma unroll
    for (int i = 0; i < 4; ++i) {
        const float* ap = A + (size_t)(r_st + 32 * i) * S_ + c8 * 8;
        paf[i][0] = *(const float4*)ap;
        paf[i][1] = *(const float4*)(ap + 4);
    }
#pragma unroll
    for (int i = 0; i < 2; ++i)
        pb[i] = *(const uint4*)(Bt + (size_t)(r_st + 32 * i) * S_ + c8 * 8);

    f32x4 acc[2][4] = {};
    for (int k0 = 0; k0 < S_; k0 += 64) {
        __syncthreads();
#pragma unroll
        for (int i = 0; i < 4; ++i)
            *(uint4*)&As[r_st + 32 * i][c8 * 8] = pack8(paf[i][0], paf[i][1]);
#pragma unroll
        for (int i = 0; i < 2; ++i)
            *(uint4*)&Bs[r_st + 32 * i][c8 * 8] = pb[i];
        __syncthreads();
        if (k0 + 64 < S_) {
#pragma unroll
            for (int i = 0; i < 4; ++i) {
                const float* ap = A + (size_t)(r_st + 32 * i) * S_ + k0 + 64 + c8 * 8;
                paf[i][0] = *(const float4*)ap;
                paf[i][1] = *(const float4*)(ap + 4);
            }
#pragma unroll
            for (int i = 0; i < 2; ++i)
                pb[i] = *(const uint4*)(Bt + (size_t)(r_st + 32 * i) * S_ + k0 + 64 + c8 * 8);
        }
#pragma unroll
        for (int kc = 0; kc < 2; ++kc) {
            bf16x8 af[2], bfr[4];
#pragma unroll
            for (int mi = 0; mi < 2; ++mi)
                af[mi] = *(const bf16x8*)&As[w * 32 + mi * 16 + ln][kc * 32 + quad * 8];
#pragma unroll
            for (int ni = 0; ni < 4; ++ni)
                bfr[ni] = *(const bf16x8*)&Bs[ni * 16 + ln][kc * 32 + quad * 8];
#pragma unroll
            for (int mi = 0; mi < 2; ++mi)
#pragma unroll
                for (int ni = 0; ni < 4; ++ni)
                    acc[mi][ni] = __builtin_amdgcn_mfma_f32_16x16x32_bf16(
                        af[mi], bfr[ni], acc[mi][ni], 0, 0, 0);
        }
    }

    const float cs = 0.03608439182435161f * 1.4426950408889634f;  // 1/sqrt(E)*log2e
    short (*Epi)[68] = (short(*)[68])smem;
    __syncthreads();
#pragma unroll
    for (int mi = 0; mi < 2; ++mi)
#pragma unroll
        for (int ni = 0; ni < 4; ++ni)
#pragma unroll
            for (int r = 0; r < 4; ++r)
                Epi[w * 32 + mi * 16 + quad * 4 + r][ni * 16 + ln] =
                    f2bf_hu(acc[mi][ni][r] * cs);
    __syncthreads();
    // 64 B per thread, fully covering lines pairwise
    int row = tid >> 1, half = tid & 1;
    short* dst = qvb + ((size_t)(b * H_ + h) * S_ + m0 + row) * P_ + half * 32;
#pragma unroll
    for (int c = 0; c < 4; ++c) {
        uint2 a = *(const uint2*)&Epi[row][half * 32 + c * 8];
        uint2 bq = *(const uint2*)&Epi[row][half * 32 + c * 8 + 4];
        *(uint4*)(dst + c * 8) = make_uint4(a.x, a.y, bq.x, bq.y);
    }
}

// ---------------------------------------------------------------------------
// Stage 3: flash attention, fixed-max softmax (P = exp2(s), scale*log2e in
// qvb). Paired q-tiles (qbA=bx, qbB=15-bx): every block 17 steps. grid (8,96).
// ---------------------------------------------------------------------------
__device__ __forceinline__ void flash_step(
    const bf16x8 (&qf)[2], bool diag, int w, int quad, int ln,
    short (*Ks)[72], short (*Vts)[72], short (*Ps)[72],
    f32x4 (&o)[4], float (&lsum)[4])
{
    f32x4 s[4] = {};
#pragma unroll
    for (int kc = 0; kc < 2; ++kc)
#pragma unroll
        for (int ni = 0; ni < 4; ++ni) {
            bf16x8 kf = *(const bf16x8*)&Ks[ni * 16 + ln][kc * 32 + quad * 8];
            s[ni] = __builtin_amdgcn_mfma_f32_16x16x32_bf16(qf[kc], kf, s[ni], 0, 0, 0);
        }
#pragma unroll
    for (int ni = 0; ni < 4; ++ni)
#pragma unroll
        for (int r = 0; r < 4; ++r) {
            bool msk = diag && (ni * 16 + ln) > (w * 16 + quad * 4 + r);
            float p = msk ? 0.f : __builtin_amdgcn_exp2f(s[ni][r]);
            lsum[r] += p;
            Ps[w * 16 + quad * 4 + r][ni * 16 + ln] = f2bf_hu(p);
        }
    // wave-private Ps rows: same-wave DS ordering suffices
#pragma unroll
    for (int kc = 0; kc < 2; ++kc) {
        bf16x8 pa = *(const bf16x8*)&Ps[w * 16 + ln][kc * 32 + quad * 8];
#pragma unroll
        for (int ni = 0; ni < 4; ++ni) {
            bf16x8 vb = *(const bf16x8*)&Vts[ni * 16 + ln][kc * 32 + quad * 8];
            o[ni] = __builtin_amdgcn_mfma_f32_16x16x32_bf16(pa, vb, o[ni], 0, 0, 0);
        }
    }
}

__global__ __launch_bounds__(256) void flash_mfma(
    const short* __restrict__ kb,
    const short* __restrict__ qvb,
    const short* __restrict__ vTb,
    short* __restrict__ attn2)
{
    __shared__ short Ks[64][72];
    __shared__ short Vts[64][72];
    __shared__ short Ps[64][72];

    const int tid = threadIdx.x;
    const int w = tid >> 6, lane = tid & 63, quad = lane >> 4, ln = lane & 15;
    const int qbA = blockIdx.x;
    const int qbB = 15 - qbA;
    const int bh = blockIdx.y;
    const int b = bh / H_, h = bh % H_;

    const short* Q  = kb  + (size_t)bh * S_ * P_;
    const short* K  = qvb + (size_t)bh * S_ * P_;
    const short* Vt = vTb + (size_t)bh * P_ * S_;

    bf16x8 qfA[2], qfB[2];
    {
        const short* qa = Q + (size_t)(qbA * 64 + w * 16 + ln) * P_ + quad * 8;
        const short* qc = Q + (size_t)(qbB * 64 + w * 16 + ln) * P_ + quad * 8;
        qfA[0] = *(const bf16x8*)(qa);
        qfA[1] = *(const bf16x8*)(qa + 32);
        qfB[0] = *(const bf16x8*)(qc);
        qfB[1] = *(const bf16x8*)(qc + 32);
    }

    f32x4 oA[4] = {}, oB[4] = {};
    float lA[4] = {}, lB[4] = {};

    const int r_st = tid >> 3, c8 = tid & 7;
    uint4 pk[2], pv[2];
#pragma unroll
    for (int i = 0; i < 2; ++i) {
        pk[i] = *(const uint4*)(K + (size_t)(r_st + 32 * i) * P_ + c8 * 8);
        pv[i] = *(const uint4*)(Vt + (size_t)(r_st + 32 * i) * S_ + c8 * 8);
    }

    for (int jt = 0; jt <= qbB; ++jt) {
        __syncthreads();
#pragma unroll
        for (int i = 0; i < 2; ++i) {
            *(uint4*)&Ks[r_st + 32 * i][c8 * 8]  = pk[i];
            *(uint4*)&Vts[r_st + 32 * i][c8 * 8] = pv[i];
        }
        __syncthreads();
        if (jt < qbB) {
            int jn = jt + 1;
#pragma unroll
            for (int i = 0; i < 2; ++i) {
                pk[i] = *(const uint4*)(K + (size_t)(jn * 64 + r_st + 32 * i) * P_ + c8 * 8);
                pv[i] = *(const uint4*)(Vt + (size_t)(r_st + 32 * i) * S_ + jn * 64 + c8 * 8);
            }
        }
        flash_step(qfB, jt == qbB, w, quad, ln, Ks, Vts, Ps, oB, lB);
        if (jt <= qbA)
            flash_step(qfA, jt == qbA, w, quad, ln, Ks, Vts, Ps, oA, lA);
    }

#pragma unroll
    for (int r = 0; r < 4; ++r) {
#pragma unroll
        for (int off = 1; off < 16; off <<= 1) {
            lA[r] += __shfl_xor(lA[r], off, 16);
            lB[r] += __shfl_xor(lB[r], off, 16);
        }
    }

    const size_t HP = H_ * P_;
#pragma unroll
    for (int r = 0; r < 4; ++r) {
        float invA = 1.0f / lA[r], invB = 1.0f / lB[r];
        int giA = qbA * 64 + w * 16 + quad * 4 + r;
        int giB = qbB * 64 + w * 16 + quad * 4 + r;
#pragma unroll
        for (int ni = 0; ni < 4; ++ni) {
            attn2[((size_t)b * S_ + giA) * HP + h * P_ + ni * 16 + ln] = f2bf_hu(oA[ni][r] * invA);
            attn2[((size_t)b * S_ + giB) * HP + h * P_ + ni * 16 + ln] = f2bf_hu(oB[ni][r] * invB);
        }
    }
}

// ---------------------------------------------------------------------------
// Stage 4: out(8192x768) = attn2 @ lifting. 64x128 tiles, 768 blocks:
// grid (128, 6). fp32 out (lines fully covered per quad).
// ---------------------------------------------------------------------------
__global__ __launch_bounds__(256) void lift_mfma(
    const short* __restrict__ attn2,
    const short* __restrict__ liftT,
    float* __restrict__ outp)
{
    __shared__ short smem[64 * 72 + 128 * 72];
    short (*As)[72] = (short(*)[72])smem;
    short (*Bs)[72] = (short(*)[72])(smem + 64 * 72);
    const int tid = threadIdx.x;
    const int w = tid >> 6, lane = tid & 63, quad = lane >> 4, ln = lane & 15;
    const int wr = (w >> 1) * 32, wc = (w & 1) * 64;
    const int m0 = blockIdx.x * 64, n0 = blockIdx.y * 128;
    const int r_st = tid >> 3, c8 = tid & 7;

    const short* A  = attn2 + (size_t)m0 * E_;
    const short* Bt = liftT + (size_t)n0 * E_;

    uint4 pa[2], pb[4];
#pragma unroll
    for (int i = 0; i < 2; ++i)
        pa[i] = *(const uint4*)(A + (size_t)(r_st + 32 * i) * E_ + c8 * 8);
#pragma unroll
    for (int i = 0; i < 4; ++i)
        pb[i] = *(const uint4*)(Bt + (size_t)(r_st + 32 * i) * E_ + c8 * 8);

    f32x4 acc[2][4] = {};
    for (int k0 = 0; k0 < E_; k0 += 64) {
        __syncthreads();
#pragma unroll
        for (int i = 0; i < 2; ++i)
            *(uint4*)&As[r_st + 32 * i][c8 * 8] = pa[i];
#pragma unroll
        for (int i = 0; i < 4; ++i)
            *(uint4*)&Bs[r_st + 32 * i][c8 * 8] = pb[i];
        __syncthreads();
        if (k0 + 64 < E_) {
#pragma unroll
            for (int i = 0; i < 2; ++i)
                pa[i] = *(const uint4*)(A + (size_t)(r_st + 32 * i) * E_ + k0 + 64 + c8 * 8);
#pragma unroll
            for (int i = 0; i < 4; ++i)
                pb[i] = *(const uint4*)(Bt + (size_t)(r_st + 32 * i) * E_ + k0 + 64 + c8 * 8);
        }
#pragma unroll
        for (int kc = 0; kc < 2; ++kc) {
            bf16x8 af[2], bfr[4];
#pragma unroll
            for (int mi = 0; mi < 2; ++mi)
                af[mi] = *(const bf16x8*)&As[wr + mi * 16 + ln][kc * 32 + quad * 8];
#pragma unroll
            for (int ni = 0; ni < 4; ++ni)
                bfr[ni] = *(const bf16x8*)&Bs[wc + ni * 16 + ln][kc * 32 + quad * 8];
#pragma unroll
            for (int mi = 0; mi < 2; ++mi)
#pragma unroll
                for (int ni = 0; ni < 4; ++ni)
                    acc[mi][ni] = __builtin_amdgcn_mfma_f32_16x16x32_bf16(
                        af[mi], bfr[ni], acc[mi][ni], 0, 0, 0);
        }
    }

#pragma unroll
    for (int mi = 0; mi < 2; ++mi)
#pragma unroll
        for (int ni = 0; ni < 4; ++ni)
#pragma unroll
            for (int r = 0; r < 4; ++r) {
                int m = m0 + wr + mi * 16 + quad * 4 + r;
                int n = n0 + wc + ni * 16 + ln;
                outp[(size_t)m * E_ + n] = acc[mi][ni][r];
            }
}

extern "C" void kernel_launch(void* const* d_in, const int* in_sizes, int n_in,
                              void* d_out, int out_size, void* d_ws, size_t ws_size,
                              hipStream_t stream) {
    (void)in_sizes; (void)n_in; (void)out_size; (void)ws_size;
    const float* x       = (const float*)d_in[0];
    const float* kproj   = (const float*)d_in[1];
    const float* vproj   = (const float*)d_in[2];
    const float* qheads  = (const float*)d_in[3];
    const float* lifting = (const float*)d_in[4];
    float* out = (float*)d_out;

    short* ws = (short*)d_ws;
    const size_t N_W  = (size_t)H_ * P_ * E_;
    const size_t N_L  = (size_t)E_ * E_;
    const size_t N_KV = (size_t)B_ * H_ * S_ * P_;

    short* kTw   = ws;  ws += N_W;
    short* vTw   = ws;  ws += N_W;
    short* liftT = ws;  ws += N_L;
    short* kb    = ws;  ws += N_KV;
    short* vTb   = ws;  ws += N_KV;
    short* qvb   = ws;  ws += N_KV;
    short* attn2 = ws;  ws += N_KV;

    conv_T_kernel<<<dim3(E_ / 64, P_ / 64, H_), 256, 0, stream>>>(kproj, kTw, E_, P_);
    conv_T_kernel<<<dim3(E_ / 64, P_ / 64, H_), 256, 0, stream>>>(vproj, vTw, E_, P_);
    conv_T_kernel<<<dim3(E_ / 64, E_ / 64, 1), 256, 0, stream>>>(lifting, liftT, E_, E_);

    proj_mfma<<<dim3((B_ * S_) / 128, E_ / 128, 2), 256, 0, stream>>>(x, kTw, vTw, kb, vTb);
    qv_mfma<<<dim3(S_ / 128, H_, B_), 256, 0, stream>>>(qheads, vTb, qvb);
    flash_mfma<<<dim3(8, B_ * H_), 256, 0, stream>>>(kb, qvb, vTb, attn2);
    lift_mfma<<<dim3((B_ * S_) / 64, E_ / 128), 256, 0, stream>>>(attn2, liftT, out);
}

// Round 6
// 383.260 us; speedup vs baseline: 1.1563x; 1.0122x over previous
//
#include <hip/hip_runtime.h>
#include <math.h>

#define B_ 8
#define S_ 1024
#define E_ 768
#define H_ 12
#define P_ 64

typedef __attribute__((ext_vector_type(8))) short bf16x8;
typedef __attribute__((ext_vector_type(4))) float f32x4;

__device__ __forceinline__ short f2bf(float f) {        // RNE
    union { float f; unsigned u; } v; v.f = f;
    unsigned r = v.u + 0x7FFFu + ((v.u >> 16) & 1u);
    return (short)(r >> 16);
}
__device__ __forceinline__ short f2bf_hu(float f) {     // round-half-away (cheap)
    union { float f; unsigned u; } v; v.f = f;
    return (short)((v.u + 0x8000u) >> 16);
}
__device__ __forceinline__ unsigned bfu(float f) {
    union { float f; unsigned u; } v; v.f = f;
    return (v.u + 0x8000u) >> 16;
}
__device__ __forceinline__ uint4 pack8(float4 a, float4 b) {
    uint4 r;
    r.x = bfu(a.x) | (bfu(a.y) << 16);
    r.y = bfu(a.z) | (bfu(a.w) << 16);
    r.z = bfu(b.x) | (bfu(b.y) << 16);
    r.w = bfu(b.z) | (bfu(b.w) << 16);
    return r;
}

// ---------------------------------------------------------------------------
// fp32 [batch][R][C] -> bf16 [batch][C][R] transpose (weights only — tiny).
// ---------------------------------------------------------------------------
__global__ __launch_bounds__(256) void conv_T_kernel(
    const float* __restrict__ src0, short* __restrict__ dst0, int R, int C)
{
    __shared__ short T[64][72];
    const int t = threadIdx.x;
    const int r0 = blockIdx.x * 64, c0 = blockIdx.y * 64;
    const size_t bo = (size_t)blockIdx.z * R * C;
    const float* src = src0 + bo;
    short* dst = dst0 + bo;
#pragma unroll
    for (int i = 0; i < 4; ++i) {
        int id = i * 256 + t;
        int r = id >> 4, c4 = id & 15;
        float4 f = *(const float4*)(src + (size_t)(r0 + r) * C + c0 + c4 * 4);
        T[c4 * 4 + 0][r] = f2bf(f.x);
        T[c4 * 4 + 1][r] = f2bf(f.y);
        T[c4 * 4 + 2][r] = f2bf(f.z);
        T[c4 * 4 + 3][r] = f2bf(f.w);
    }
    __syncthreads();
#pragma unroll
    for (int i = 0; i < 2; ++i) {
        int id = i * 256 + t;
        int cc = id >> 3, r8 = id & 7;
        *(uint4*)(dst + (size_t)(c0 + cc) * R + r0 + r8 * 8) = *(const uint4*)&T[cc][r8 * 8];
    }
}

__device__ __forceinline__ void epi_row_out(const short (*Epi)[132], int row,
                                            int half, short* dst)
{
#pragma unroll
    for (int c = 0; c < 8; ++c) {
        uint2 a = *(const uint2*)&Epi[row][half * 64 + c * 8];
        uint2 b = *(const uint2*)&Epi[row][half * 64 + c * 8 + 4];
        *(uint4*)(dst + c * 8) = make_uint4(a.x, a.y, b.x, b.y);
    }
}

// ---------------------------------------------------------------------------
// Stage 1: k = x @ Wk, v = x @ Wv (x fp32, converted in-register).
// grid (64, 6, 2) = 768 blocks.
// ---------------------------------------------------------------------------
__global__ __launch_bounds__(256) void proj_mfma(
    const float* __restrict__ x,
    const short* __restrict__ kTw,
    const short* __restrict__ vTw,
    short* __restrict__ kb,
    short* __restrict__ vTb)
{
    __shared__ short smem[128 * 72 * 2];
    short (*As)[72] = (short(*)[72])smem;
    short (*Bs)[72] = (short(*)[72])(smem + 128 * 72);
    const int tid = threadIdx.x;
    const int w = tid >> 6, lane = tid & 63, quad = lane >> 4, ln = lane & 15;
    const int wr = (w >> 1) * 64, wc = (w & 1) * 64;
    const int m0 = blockIdx.x * 128, n0 = blockIdx.y * 128;
    const int z = blockIdx.z;
    const int r_st = tid >> 3, c8 = tid & 7;

    const float* A  = x + (size_t)m0 * E_;
    const short* Bt = (z ? vTw : kTw) + (size_t)n0 * E_;

    float4 paf[4][2];
    uint4 pb[4];
#pragma unroll
    for (int i = 0; i < 4; ++i) {
        const float* ap = A + (size_t)(r_st + 32 * i) * E_ + c8 * 8;
        paf[i][0] = *(const float4*)ap;
        paf[i][1] = *(const float4*)(ap + 4);
        pb[i] = *(const uint4*)(Bt + (size_t)(r_st + 32 * i) * E_ + c8 * 8);
    }
    f32x4 acc[4][4] = {};
    for (int k0 = 0; k0 < E_; k0 += 64) {
        __syncthreads();
#pragma unroll
        for (int i = 0; i < 4; ++i) {
            *(uint4*)&As[r_st + 32 * i][c8 * 8] = pack8(paf[i][0], paf[i][1]);
            *(uint4*)&Bs[r_st + 32 * i][c8 * 8] = pb[i];
        }
        __syncthreads();
        if (k0 + 64 < E_) {
#pragma unroll
            for (int i = 0; i < 4; ++i) {
                const float* ap = A + (size_t)(r_st + 32 * i) * E_ + k0 + 64 + c8 * 8;
                paf[i][0] = *(const float4*)ap;
                paf[i][1] = *(const float4*)(ap + 4);
                pb[i] = *(const uint4*)(Bt + (size_t)(r_st + 32 * i) * E_ + k0 + 64 + c8 * 8);
            }
        }
#pragma unroll
        for (int kc = 0; kc < 2; ++kc) {
            bf16x8 af[4], bfr[4];
#pragma unroll
            for (int mi = 0; mi < 4; ++mi)
                af[mi] = *(const bf16x8*)&As[wr + mi * 16 + ln][kc * 32 + quad * 8];
#pragma unroll
            for (int ni = 0; ni < 4; ++ni)
                bfr[ni] = *(const bf16x8*)&Bs[wc + ni * 16 + ln][kc * 32 + quad * 8];
#pragma unroll
            for (int mi = 0; mi < 4; ++mi)
#pragma unroll
                for (int ni = 0; ni < 4; ++ni)
                    acc[mi][ni] = __builtin_amdgcn_mfma_f32_16x16x32_bf16(
                        af[mi], bfr[ni], acc[mi][ni], 0, 0, 0);
        }
    }

    const int b = m0 >> 10, sb = m0 & 1023;
    short (*Epi)[132] = (short(*)[132])smem;
    __syncthreads();
    if (z == 0) {
#pragma unroll
        for (int mi = 0; mi < 4; ++mi)
#pragma unroll
            for (int ni = 0; ni < 4; ++ni)
#pragma unroll
                for (int r = 0; r < 4; ++r)
                    Epi[wr + mi * 16 + quad * 4 + r][wc + ni * 16 + ln] =
                        f2bf_hu(acc[mi][ni][r]);
        __syncthreads();
        int s_loc = tid & 127, half = tid >> 7;
        int h = (n0 >> 6) + half;
        short* dst = kb + ((size_t)(b * H_ + h) * S_ + sb + s_loc) * P_;
        epi_row_out(Epi, s_loc, half, dst);
    } else {
#pragma unroll
        for (int mi = 0; mi < 4; ++mi)
#pragma unroll
            for (int ni = 0; ni < 4; ++ni) {
                ushort4 u;
                u.x = (unsigned short)f2bf_hu(acc[mi][ni][0]);
                u.y = (unsigned short)f2bf_hu(acc[mi][ni][1]);
                u.z = (unsigned short)f2bf_hu(acc[mi][ni][2]);
                u.w = (unsigned short)f2bf_hu(acc[mi][ni][3]);
                *(ushort4*)&Epi[wc + ni * 16 + ln][wr + mi * 16 + quad * 4] = u;
            }
        __syncthreads();
        int c_loc = tid & 127, half = tid >> 7;
        int h = (n0 >> 6) + (c_loc >> 6), p = c_loc & 63;
        short* dst = vTb + ((size_t)(b * H_ + h) * P_ + p) * S_ + sb + half * 64;
        epi_row_out(Epi, c_loc, half, dst);
    }
}

// ---------------------------------------------------------------------------
// Stage 2: qv[b,h] = q_heads[h] @ v[b,h] (qh fp32 in-register). grid (8,12,8).
// ---------------------------------------------------------------------------
__global__ __launch_bounds__(256) void qv_mfma(
    const float* __restrict__ qh,
    const short* __restrict__ vTb,
    short* __restrict__ qvb)
{
    __shared__ short smem[128 * 72 + 64 * 72];
    short (*As)[72] = (short(*)[72])smem;
    short (*Bs)[72] = (short(*)[72])(smem + 128 * 72);
    const int tid = threadIdx.x;
    const int w = tid >> 6, lane = tid & 63, quad = lane >> 4, ln = lane & 15;
    const int m0 = blockIdx.x * 128;
    const int h = blockIdx.y, b = blockIdx.z;
    const int r_st = tid >> 3, c8 = tid & 7;

    const float* A  = qh + (size_t)h * S_ * S_ + (size_t)m0 * S_;
    const short* Bt = vTb + (size_t)(b * H_ + h) * P_ * S_;

    float4 paf[4][2];
    uint4 pb[2];
#pragma unroll
    for (int i = 0; i < 4; ++i) {
        const float* ap = A + (size_t)(r_st + 32 * i) * S_ + c8 * 8;
        paf[i][0] = *(const float4*)ap;
        paf[i][1] = *(const float4*)(ap + 4);
    }
#pragma unroll
    for (int i = 0; i < 2; ++i)
        pb[i] = *(const uint4*)(Bt + (size_t)(r_st + 32 * i) * S_ + c8 * 8);

    f32x4 acc[2][4] = {};
    for (int k0 = 0; k0 < S_; k0 += 64) {
        __syncthreads();
#pragma unroll
        for (int i = 0; i < 4; ++i)
            *(uint4*)&As[r_st + 32 * i][c8 * 8] = pack8(paf[i][0], paf[i][1]);
#pragma unroll
        for (int i = 0; i < 2; ++i)
            *(uint4*)&Bs[r_st + 32 * i][c8 * 8] = pb[i];
        __syncthreads();
        if (k0 + 64 < S_) {
#pragma unroll
            for (int i = 0; i < 4; ++i) {
                const float* ap = A + (size_t)(r_st + 32 * i) * S_ + k0 + 64 + c8 * 8;
                paf[i][0] = *(const float4*)ap;
                paf[i][1] = *(const float4*)(ap + 4);
            }
#pragma unroll
            for (int i = 0; i < 2; ++i)
                pb[i] = *(const uint4*)(Bt + (size_t)(r_st + 32 * i) * S_ + k0 + 64 + c8 * 8);
        }
#pragma unroll
        for (int kc = 0; kc < 2; ++kc) {
            bf16x8 af[2], bfr[4];
#pragma unroll
            for (int mi = 0; mi < 2; ++mi)
                af[mi] = *(const bf16x8*)&As[w * 32 + mi * 16 + ln][kc * 32 + quad * 8];
#pragma unroll
            for (int ni = 0; ni < 4; ++ni)
                bfr[ni] = *(const bf16x8*)&Bs[ni * 16 + ln][kc * 32 + quad * 8];
#pragma unroll
            for (int mi = 0; mi < 2; ++mi)
#pragma unroll
                for (int ni = 0; ni < 4; ++ni)
                    acc[mi][ni] = __builtin_amdgcn_mfma_f32_16x16x32_bf16(
                        af[mi], bfr[ni], acc[mi][ni], 0, 0, 0);
        }
    }

    const float cs = 0.03608439182435161f * 1.4426950408889634f;  // 1/sqrt(E)*log2e
    short (*Epi)[68] = (short(*)[68])smem;
    __syncthreads();
#pragma unroll
    for (int mi = 0; mi < 2; ++mi)
#pragma unroll
        for (int ni = 0; ni < 4; ++ni)
#pragma unroll
            for (int r = 0; r < 4; ++r)
                Epi[w * 32 + mi * 16 + quad * 4 + r][ni * 16 + ln] =
                    f2bf_hu(acc[mi][ni][r] * cs);
    __syncthreads();
    int row = tid >> 1, half = tid & 1;
    short* dst = qvb + ((size_t)(b * H_ + h) * S_ + m0 + row) * P_ + half * 32;
#pragma unroll
    for (int c = 0; c < 4; ++c) {
        uint2 a = *(const uint2*)&Epi[row][half * 32 + c * 8];
        uint2 bq = *(const uint2*)&Epi[row][half * 32 + c * 8 + 4];
        *(uint4*)(dst + c * 8) = make_uint4(a.x, a.y, bq.x, bq.y);
    }
}

// ---------------------------------------------------------------------------
// Stage 3: flash attention, fixed-max softmax. Paired q-tiles (every block
// 17 steps). Double-buffered K/V LDS -> ONE barrier per j-step; the vmcnt
// wait for prefetched K/V sits AFTER compute (store to the alternate buffer).
// grid (96, 8): bh fastest -> the 8 blocks sharing one bh's K/V stream get
// linear ids = same mod 8 -> same XCD (L2-local stream).
// ---------------------------------------------------------------------------
__device__ __forceinline__ void flash_step(
    const bf16x8 (&qf)[2], bool diag, int w, int quad, int ln,
    const short (*Ks)[72], const short (*Vts)[72], short (*Ps)[72],
    f32x4 (&o)[4], float (&lsum)[4])
{
    f32x4 s[4] = {};
#pragma unroll
    for (int kc = 0; kc < 2; ++kc)
#pragma unroll
        for (int ni = 0; ni < 4; ++ni) {
            bf16x8 kf = *(const bf16x8*)&Ks[ni * 16 + ln][kc * 32 + quad * 8];
            s[ni] = __builtin_amdgcn_mfma_f32_16x16x32_bf16(qf[kc], kf, s[ni], 0, 0, 0);
        }
#pragma unroll
    for (int ni = 0; ni < 4; ++ni)
#pragma unroll
        for (int r = 0; r < 4; ++r) {
            bool msk = diag && (ni * 16 + ln) > (w * 16 + quad * 4 + r);
            float p = msk ? 0.f : __builtin_amdgcn_exp2f(s[ni][r]);
            lsum[r] += p;
            Ps[w * 16 + quad * 4 + r][ni * 16 + ln] = f2bf_hu(p);
        }
    // wave-private Ps rows: same-wave DS ordering suffices
#pragma unroll
    for (int kc = 0; kc < 2; ++kc) {
        bf16x8 pa = *(const bf16x8*)&Ps[w * 16 + ln][kc * 32 + quad * 8];
#pragma unroll
        for (int ni = 0; ni < 4; ++ni) {
            bf16x8 vb = *(const bf16x8*)&Vts[ni * 16 + ln][kc * 32 + quad * 8];
            o[ni] = __builtin_amdgcn_mfma_f32_16x16x32_bf16(pa, vb, o[ni], 0, 0, 0);
        }
    }
}

__global__ __launch_bounds__(256) void flash_mfma(
    const short* __restrict__ kb,
    const short* __restrict__ qvb,
    const short* __restrict__ vTb,
    short* __restrict__ attn2)
{
    __shared__ short Ks[2][64][72];
    __shared__ short Vts[2][64][72];
    __shared__ short Ps[64][72];

    const int tid = threadIdx.x;
    const int w = tid >> 6, lane = tid & 63, quad = lane >> 4, ln = lane & 15;
    const int bh = blockIdx.x;           // fastest dim -> XCD clustering per bh
    const int qbA = blockIdx.y;          // 0..7
    const int qbB = 15 - qbA;            // 8..15
    const int b = bh / H_, h = bh % H_;

    const short* Q  = kb  + (size_t)bh * S_ * P_;
    const short* K  = qvb + (size_t)bh * S_ * P_;
    const short* Vt = vTb + (size_t)bh * P_ * S_;

    bf16x8 qfA[2], qfB[2];
    {
        const short* qa = Q + (size_t)(qbA * 64 + w * 16 + ln) * P_ + quad * 8;
        const short* qc = Q + (size_t)(qbB * 64 + w * 16 + ln) * P_ + quad * 8;
        qfA[0] = *(const bf16x8*)(qa);
        qfA[1] = *(const bf16x8*)(qa + 32);
        qfB[0] = *(const bf16x8*)(qc);
        qfB[1] = *(const bf16x8*)(qc + 32);
    }

    f32x4 oA[4] = {}, oB[4] = {};
    float lA[4] = {}, lB[4] = {};

    const int r_st = tid >> 3, c8 = tid & 7;
    uint4 pk[2], pv[2];
#pragma unroll
    for (int i = 0; i < 2; ++i) {
        pk[i] = *(const uint4*)(K + (size_t)(r_st + 32 * i) * P_ + c8 * 8);
        pv[i] = *(const uint4*)(Vt + (size_t)(r_st + 32 * i) * S_ + c8 * 8);
    }
#pragma unroll
    for (int i = 0; i < 2; ++i) {
        *(uint4*)&Ks[0][r_st + 32 * i][c8 * 8]  = pk[i];
        *(uint4*)&Vts[0][r_st + 32 * i][c8 * 8] = pv[i];
    }
    __syncthreads();

    for (int jt = 0; jt <= qbB; ++jt) {
        const int cur = jt & 1;
        if (jt < qbB) {
            int jn = jt + 1;
#pragma unroll
            for (int i = 0; i < 2; ++i) {
                pk[i] = *(const uint4*)(K + (size_t)(jn * 64 + r_st + 32 * i) * P_ + c8 * 8);
                pv[i] = *(const uint4*)(Vt + (size_t)(r_st + 32 * i) * S_ + jn * 64 + c8 * 8);
            }
        }
        flash_step(qfB, jt == qbB, w, quad, ln, Ks[cur], Vts[cur], Ps, oB, lB);
        if (jt <= qbA)
            flash_step(qfA, jt == qbA, w, quad, ln, Ks[cur], Vts[cur], Ps, oA, lA);
        if (jt < qbB) {
            const int nxt = cur ^ 1;
#pragma unroll
            for (int i = 0; i < 2; ++i) {
                *(uint4*)&Ks[nxt][r_st + 32 * i][c8 * 8]  = pk[i];
                *(uint4*)&Vts[nxt][r_st + 32 * i][c8 * 8] = pv[i];
            }
        }
        __syncthreads();
    }

#pragma unroll
    for (int r = 0; r < 4; ++r) {
#pragma unroll
        for (int off = 1; off < 16; off <<= 1) {
            lA[r] += __shfl_xor(lA[r], off, 16);
            lB[r] += __shfl_xor(lB[r], off, 16);
        }
    }

    const size_t HP = H_ * P_;
#pragma unroll
    for (int r = 0; r < 4; ++r) {
        float invA = 1.0f / lA[r], invB = 1.0f / lB[r];
        int giA = qbA * 64 + w * 16 + quad * 4 + r;
        int giB = qbB * 64 + w * 16 + quad * 4 + r;
#pragma unroll
        for (int ni = 0; ni < 4; ++ni) {
            attn2[((size_t)b * S_ + giA) * HP + h * P_ + ni * 16 + ln] = f2bf_hu(oA[ni][r] * invA);
            attn2[((size_t)b * S_ + giB) * HP + h * P_ + ni * 16 + ln] = f2bf_hu(oB[ni][r] * invB);
        }
    }
}

// ---------------------------------------------------------------------------
// Stage 4: out = attn2 @ lifting. 64x128 tiles, grid (128, 6). fp32 out.
// ---------------------------------------------------------------------------
__global__ __launch_bounds__(256) void lift_mfma(
    const short* __restrict__ attn2,
    const short* __restrict__ liftT,
    float* __restrict__ outp)
{
    __shared__ short smem[64 * 72 + 128 * 72];
    short (*As)[72] = (short(*)[72])smem;
    short (*Bs)[72] = (short(*)[72])(smem + 64 * 72);
    const int tid = threadIdx.x;
    const int w = tid >> 6, lane = tid & 63, quad = lane >> 4, ln = lane & 15;
    const int wr = (w >> 1) * 32, wc = (w & 1) * 64;
    const int m0 = blockIdx.x * 64, n0 = blockIdx.y * 128;
    const int r_st = tid >> 3, c8 = tid & 7;

    const short* A  = attn2 + (size_t)m0 * E_;
    const short* Bt = liftT + (size_t)n0 * E_;

    uint4 pa[2], pb[4];
#pragma unroll
    for (int i = 0; i < 2; ++i)
        pa[i] = *(const uint4*)(A + (size_t)(r_st + 32 * i) * E_ + c8 * 8);
#pragma unroll
    for (int i = 0; i < 4; ++i)
        pb[i] = *(const uint4*)(Bt + (size_t)(r_st + 32 * i) * E_ + c8 * 8);

    f32x4 acc[2][4] = {};
    for (int k0 = 0; k0 < E_; k0 += 64) {
        __syncthreads();
#pragma unroll
        for (int i = 0; i < 2; ++i)
            *(uint4*)&As[r_st + 32 * i][c8 * 8] = pa[i];
#pragma unroll
        for (int i = 0; i < 4; ++i)
            *(uint4*)&Bs[r_st + 32 * i][c8 * 8] = pb[i];
        __syncthreads();
        if (k0 + 64 < E_) {
#pragma unroll
            for (int i = 0; i < 2; ++i)
                pa[i] = *(const uint4*)(A + (size_t)(r_st + 32 * i) * E_ + k0 + 64 + c8 * 8);
#pragma unroll
            for (int i = 0; i < 4; ++i)
                pb[i] = *(const uint4*)(Bt + (size_t)(r_st + 32 * i) * E_ + k0 + 64 + c8 * 8);
        }
#pragma unroll
        for (int kc = 0; kc < 2; ++kc) {
            bf16x8 af[2], bfr[4];
#pragma unroll
            for (int mi = 0; mi < 2; ++mi)
                af[mi] = *(const bf16x8*)&As[wr + mi * 16 + ln][kc * 32 + quad * 8];
#pragma unroll
            for (int ni = 0; ni < 4; ++ni)
                bfr[ni] = *(const bf16x8*)&Bs[wc + ni * 16 + ln][kc * 32 + quad * 8];
#pragma unroll
            for (int mi = 0; mi < 2; ++mi)
#pragma unroll
                for (int ni = 0; ni < 4; ++ni)
                    acc[mi][ni] = __builtin_amdgcn_mfma_f32_16x16x32_bf16(
                        af[mi], bfr[ni], acc[mi][ni], 0, 0, 0);
        }
    }

#pragma unroll
    for (int mi = 0; mi < 2; ++mi)
#pragma unroll
        for (int ni = 0; ni < 4; ++ni)
#pragma unroll
            for (int r = 0; r < 4; ++r) {
                int m = m0 + wr + mi * 16 + quad * 4 + r;
                int n = n0 + wc + ni * 16 + ln;
                outp[(size_t)m * E_ + n] = acc[mi][ni][r];
            }
}

extern "C" void kernel_launch(void* const* d_in, const int* in_sizes, int n_in,
                              void* d_out, int out_size, void* d_ws, size_t ws_size,
                              hipStream_t stream) {
    (void)in_sizes; (void)n_in; (void)out_size; (void)ws_size;
    const float* x       = (const float*)d_in[0];
    const float* kproj   = (const float*)d_in[1];
    const float* vproj   = (const float*)d_in[2];
    const float* qheads  = (const float*)d_in[3];
    const float* lifting = (const float*)d_in[4];
    float* out = (float*)d_out;

    short* ws = (short*)d_ws;
    const size_t N_W  = (size_t)H_ * P_ * E_;
    const size_t N_L  = (size_t)E_ * E_;
    const size_t N_KV = (size_t)B_ * H_ * S_ * P_;

    short* kTw   = ws;  ws += N_W;
    short* vTw   = ws;  ws += N_W;
    short* liftT = ws;  ws += N_L;
    short* kb    = ws;  ws += N_KV;
    short* vTb   = ws;  ws += N_KV;
    short* qvb   = ws;  ws += N_KV;
    short* attn2 = ws;  ws += N_KV;

    conv_T_kernel<<<dim3(E_ / 64, P_ / 64, H_), 256, 0, stream>>>(kproj, kTw, E_, P_);
    conv_T_kernel<<<dim3(E_ / 64, P_ / 64, H_), 256, 0, stream>>>(vproj, vTw, E_, P_);
    conv_T_kernel<<<dim3(E_ / 64, E_ / 64, 1), 256, 0, stream>>>(lifting, liftT, E_, E_);

    proj_mfma<<<dim3((B_ * S_) / 128, E_ / 128, 2), 256, 0, stream>>>(x, kTw, vTw, kb, vTb);
    qv_mfma<<<dim3(S_ / 128, H_, B_), 256, 0, stream>>>(qheads, vTb, qvb);
    flash_mfma<<<dim3(B_ * H_, 8), 256, 0, stream>>>(kb, qvb, vTb, attn2);
    lift_mfma<<<dim3((B_ * S_) / 64, E_ / 128), 256, 0, stream>>>(attn2, liftT, out);
}

// Round 7
// 376.700 us; speedup vs baseline: 1.1764x; 1.0174x over previous
//
#include <hip/hip_runtime.h>
#include <math.h>

#define B_ 8
#define S_ 1024
#define E_ 768
#define H_ 12
#define P_ 64

typedef __attribute__((ext_vector_type(8))) short bf16x8;
typedef __attribute__((ext_vector_type(4))) float f32x4;

__device__ __forceinline__ short f2bf(float f) {        // RNE
    union { float f; unsigned u; } v; v.f = f;
    unsigned r = v.u + 0x7FFFu + ((v.u >> 16) & 1u);
    return (short)(r >> 16);
}
__device__ __forceinline__ short f2bf_hu(float f) {     // round-half-away (cheap)
    union { float f; unsigned u; } v; v.f = f;
    return (short)((v.u + 0x8000u) >> 16);
}
__device__ __forceinline__ unsigned bfu(float f) {
    union { float f; unsigned u; } v; v.f = f;
    return (v.u + 0x8000u) >> 16;
}
__device__ __forceinline__ uint4 pack8(float4 a, float4 b) {
    uint4 r;
    r.x = bfu(a.x) | (bfu(a.y) << 16);
    r.y = bfu(a.z) | (bfu(a.w) << 16);
    r.z = bfu(b.x) | (bfu(b.y) << 16);
    r.w = bfu(b.z) | (bfu(b.w) << 16);
    return r;
}

// ---------------------------------------------------------------------------
// fp32 [batch][R][C] -> bf16 [batch][C][R] transpose (weights only — tiny).
// ---------------------------------------------------------------------------
__global__ __launch_bounds__(256) void conv_T_kernel(
    const float* __restrict__ src0, short* __restrict__ dst0, int R, int C)
{
    __shared__ short T[64][72];
    const int t = threadIdx.x;
    const int r0 = blockIdx.x * 64, c0 = blockIdx.y * 64;
    const size_t bo = (size_t)blockIdx.z * R * C;
    const float* src = src0 + bo;
    short* dst = dst0 + bo;
#pragma unroll
    for (int i = 0; i < 4; ++i) {
        int id = i * 256 + t;
        int r = id >> 4, c4 = id & 15;
        float4 f = *(const float4*)(src + (size_t)(r0 + r) * C + c0 + c4 * 4);
        T[c4 * 4 + 0][r] = f2bf(f.x);
        T[c4 * 4 + 1][r] = f2bf(f.y);
        T[c4 * 4 + 2][r] = f2bf(f.z);
        T[c4 * 4 + 3][r] = f2bf(f.w);
    }
    __syncthreads();
#pragma unroll
    for (int i = 0; i < 2; ++i) {
        int id = i * 256 + t;
        int cc = id >> 3, r8 = id & 7;
        *(uint4*)(dst + (size_t)(c0 + cc) * R + r0 + r8 * 8) = *(const uint4*)&T[cc][r8 * 8];
    }
}

__device__ __forceinline__ void epi_row_out(const short (*Epi)[132], int row,
                                            int half, short* dst)
{
#pragma unroll
    for (int c = 0; c < 8; ++c) {
        uint2 a = *(const uint2*)&Epi[row][half * 64 + c * 8];
        uint2 b = *(const uint2*)&Epi[row][half * 64 + c * 8 + 4];
        *(uint4*)(dst + c * 8) = make_uint4(a.x, a.y, b.x, b.y);
    }
}

// ---------------------------------------------------------------------------
// Stage 1: k = x @ Wk, v = x @ Wv (x fp32, converted in-register).
// grid (64, 6, 2) = 768 blocks.
// ---------------------------------------------------------------------------
__global__ __launch_bounds__(256) void proj_mfma(
    const float* __restrict__ x,
    const short* __restrict__ kTw,
    const short* __restrict__ vTw,
    short* __restrict__ kb,
    short* __restrict__ vTb)
{
    __shared__ short smem[128 * 72 * 2];
    short (*As)[72] = (short(*)[72])smem;
    short (*Bs)[72] = (short(*)[72])(smem + 128 * 72);
    const int tid = threadIdx.x;
    const int w = tid >> 6, lane = tid & 63, quad = lane >> 4, ln = lane & 15;
    const int wr = (w >> 1) * 64, wc = (w & 1) * 64;
    const int m0 = blockIdx.x * 128, n0 = blockIdx.y * 128;
    const int z = blockIdx.z;
    const int r_st = tid >> 3, c8 = tid & 7;

    const float* A  = x + (size_t)m0 * E_;
    const short* Bt = (z ? vTw : kTw) + (size_t)n0 * E_;

    float4 paf[4][2];
    uint4 pb[4];
#pragma unroll
    for (int i = 0; i < 4; ++i) {
        const float* ap = A + (size_t)(r_st + 32 * i) * E_ + c8 * 8;
        paf[i][0] = *(const float4*)ap;
        paf[i][1] = *(const float4*)(ap + 4);
        pb[i] = *(const uint4*)(Bt + (size_t)(r_st + 32 * i) * E_ + c8 * 8);
    }
    f32x4 acc[4][4] = {};
    for (int k0 = 0; k0 < E_; k0 += 64) {
        __syncthreads();
#pragma unroll
        for (int i = 0; i < 4; ++i) {
            *(uint4*)&As[r_st + 32 * i][c8 * 8] = pack8(paf[i][0], paf[i][1]);
            *(uint4*)&Bs[r_st + 32 * i][c8 * 8] = pb[i];
        }
        __syncthreads();
        if (k0 + 64 < E_) {
#pragma unroll
            for (int i = 0; i < 4; ++i) {
                const float* ap = A + (size_t)(r_st + 32 * i) * E_ + k0 + 64 + c8 * 8;
                paf[i][0] = *(const float4*)ap;
                paf[i][1] = *(const float4*)(ap + 4);
                pb[i] = *(const uint4*)(Bt + (size_t)(r_st + 32 * i) * E_ + k0 + 64 + c8 * 8);
            }
        }
#pragma unroll
        for (int kc = 0; kc < 2; ++kc) {
            bf16x8 af[4], bfr[4];
#pragma unroll
            for (int mi = 0; mi < 4; ++mi)
                af[mi] = *(const bf16x8*)&As[wr + mi * 16 + ln][kc * 32 + quad * 8];
#pragma unroll
            for (int ni = 0; ni < 4; ++ni)
                bfr[ni] = *(const bf16x8*)&Bs[wc + ni * 16 + ln][kc * 32 + quad * 8];
#pragma unroll
            for (int mi = 0; mi < 4; ++mi)
#pragma unroll
                for (int ni = 0; ni < 4; ++ni)
                    acc[mi][ni] = __builtin_amdgcn_mfma_f32_16x16x32_bf16(
                        af[mi], bfr[ni], acc[mi][ni], 0, 0, 0);
        }
    }

    const int b = m0 >> 10, sb = m0 & 1023;
    short (*Epi)[132] = (short(*)[132])smem;
    __syncthreads();
    if (z == 0) {
#pragma unroll
        for (int mi = 0; mi < 4; ++mi)
#pragma unroll
            for (int ni = 0; ni < 4; ++ni)
#pragma unroll
                for (int r = 0; r < 4; ++r)
                    Epi[wr + mi * 16 + quad * 4 + r][wc + ni * 16 + ln] =
                        f2bf_hu(acc[mi][ni][r]);
        __syncthreads();
        int s_loc = tid & 127, half = tid >> 7;
        int h = (n0 >> 6) + half;
        short* dst = kb + ((size_t)(b * H_ + h) * S_ + sb + s_loc) * P_;
        epi_row_out(Epi, s_loc, half, dst);
    } else {
#pragma unroll
        for (int mi = 0; mi < 4; ++mi)
#pragma unroll
            for (int ni = 0; ni < 4; ++ni) {
                ushort4 u;
                u.x = (unsigned short)f2bf_hu(acc[mi][ni][0]);
                u.y = (unsigned short)f2bf_hu(acc[mi][ni][1]);
                u.z = (unsigned short)f2bf_hu(acc[mi][ni][2]);
                u.w = (unsigned short)f2bf_hu(acc[mi][ni][3]);
                *(ushort4*)&Epi[wc + ni * 16 + ln][wr + mi * 16 + quad * 4] = u;
            }
        __syncthreads();
        int c_loc = tid & 127, half = tid >> 7;
        int h = (n0 >> 6) + (c_loc >> 6), p = c_loc & 63;
        short* dst = vTb + ((size_t)(b * H_ + h) * P_ + p) * S_ + sb + half * 64;
        epi_row_out(Epi, c_loc, half, dst);
    }
}

// ---------------------------------------------------------------------------
// Stage 2: qv[b,h] = q_heads[h] @ v[b,h] (qh fp32 in-register). grid (8,12,8).
// ---------------------------------------------------------------------------
__global__ __launch_bounds__(256) void qv_mfma(
    const float* __restrict__ qh,
    const short* __restrict__ vTb,
    short* __restrict__ qvb)
{
    __shared__ short smem[128 * 72 + 64 * 72];
    short (*As)[72] = (short(*)[72])smem;
    short (*Bs)[72] = (short(*)[72])(smem + 128 * 72);
    const int tid = threadIdx.x;
    const int w = tid >> 6, lane = tid & 63, quad = lane >> 4, ln = lane & 15;
    const int m0 = blockIdx.x * 128;
    const int h = blockIdx.y, b = blockIdx.z;
    const int r_st = tid >> 3, c8 = tid & 7;

    const float* A  = qh + (size_t)h * S_ * S_ + (size_t)m0 * S_;
    const short* Bt = vTb + (size_t)(b * H_ + h) * P_ * S_;

    float4 paf[4][2];
    uint4 pb[2];
#pragma unroll
    for (int i = 0; i < 4; ++i) {
        const float* ap = A + (size_t)(r_st + 32 * i) * S_ + c8 * 8;
        paf[i][0] = *(const float4*)ap;
        paf[i][1] = *(const float4*)(ap + 4);
    }
#pragma unroll
    for (int i = 0; i < 2; ++i)
        pb[i] = *(const uint4*)(Bt + (size_t)(r_st + 32 * i) * S_ + c8 * 8);

    f32x4 acc[2][4] = {};
    for (int k0 = 0; k0 < S_; k0 += 64) {
        __syncthreads();
#pragma unroll
        for (int i = 0; i < 4; ++i)
            *(uint4*)&As[r_st + 32 * i][c8 * 8] = pack8(paf[i][0], paf[i][1]);
#pragma unroll
        for (int i = 0; i < 2; ++i)
            *(uint4*)&Bs[r_st + 32 * i][c8 * 8] = pb[i];
        __syncthreads();
        if (k0 + 64 < S_) {
#pragma unroll
            for (int i = 0; i < 4; ++i) {
                const float* ap = A + (size_t)(r_st + 32 * i) * S_ + k0 + 64 + c8 * 8;
                paf[i][0] = *(const float4*)ap;
                paf[i][1] = *(const float4*)(ap + 4);
            }
#pragma unroll
            for (int i = 0; i < 2; ++i)
                pb[i] = *(const uint4*)(Bt + (size_t)(r_st + 32 * i) * S_ + k0 + 64 + c8 * 8);
        }
#pragma unroll
        for (int kc = 0; kc < 2; ++kc) {
            bf16x8 af[2], bfr[4];
#pragma unroll
            for (int mi = 0; mi < 2; ++mi)
                af[mi] = *(const bf16x8*)&As[w * 32 + mi * 16 + ln][kc * 32 + quad * 8];
#pragma unroll
            for (int ni = 0; ni < 4; ++ni)
                bfr[ni] = *(const bf16x8*)&Bs[ni * 16 + ln][kc * 32 + quad * 8];
#pragma unroll
            for (int mi = 0; mi < 2; ++mi)
#pragma unroll
                for (int ni = 0; ni < 4; ++ni)
                    acc[mi][ni] = __builtin_amdgcn_mfma_f32_16x16x32_bf16(
                        af[mi], bfr[ni], acc[mi][ni], 0, 0, 0);
        }
    }

    const float cs = 0.03608439182435161f * 1.4426950408889634f;  // 1/sqrt(E)*log2e
    short (*Epi)[68] = (short(*)[68])smem;
    __syncthreads();
#pragma unroll
    for (int mi = 0; mi < 2; ++mi)
#pragma unroll
        for (int ni = 0; ni < 4; ++ni)
#pragma unroll
            for (int r = 0; r < 4; ++r)
                Epi[w * 32 + mi * 16 + quad * 4 + r][ni * 16 + ln] =
                    f2bf_hu(acc[mi][ni][r] * cs);
    __syncthreads();
    int row = tid >> 1, half = tid & 1;
    short* dst = qvb + ((size_t)(b * H_ + h) * S_ + m0 + row) * P_ + half * 32;
#pragma unroll
    for (int c = 0; c < 4; ++c) {
        uint2 a = *(const uint2*)&Epi[row][half * 32 + c * 8];
        uint2 bq = *(const uint2*)&Epi[row][half * 32 + c * 8 + 4];
        *(uint4*)(dst + c * 8) = make_uint4(a.x, a.y, bq.x, bq.y);
    }
}

// ---------------------------------------------------------------------------
// Stage 3: flash attention, fixed-max softmax. ONE 64-row q-tile per block,
// grid (96, 16) = 1536 blocks; qt = 15 - by so long blocks dispatch first and
// causal imbalance self-balances (avg 8.5 steps, ~6 blocks/CU in flight).
// Single-buffered K/V (27.6 KB LDS -> high residency). bh fastest -> XCD-
// clustered K/V streams. Wave-uniform diag branch skips mask math on 15/16
// of steps.
// ---------------------------------------------------------------------------
__device__ __forceinline__ void flash_step(
    const bf16x8 (&qf)[2], bool diag, int w, int quad, int ln,
    const short (*Ks)[72], const short (*Vts)[72], short (*Ps)[72],
    f32x4 (&o)[4], float (&lsum)[4])
{
    f32x4 s[4] = {};
#pragma unroll
    for (int kc = 0; kc < 2; ++kc)
#pragma unroll
        for (int ni = 0; ni < 4; ++ni) {
            bf16x8 kf = *(const bf16x8*)&Ks[ni * 16 + ln][kc * 32 + quad * 8];
            s[ni] = __builtin_amdgcn_mfma_f32_16x16x32_bf16(qf[kc], kf, s[ni], 0, 0, 0);
        }
    if (diag) {
#pragma unroll
        for (int ni = 0; ni < 4; ++ni)
#pragma unroll
            for (int r = 0; r < 4; ++r) {
                bool msk = (ni * 16 + ln) > (w * 16 + quad * 4 + r);
                float p = msk ? 0.f : __builtin_amdgcn_exp2f(s[ni][r]);
                lsum[r] += p;
                Ps[w * 16 + quad * 4 + r][ni * 16 + ln] = f2bf_hu(p);
            }
    } else {
#pragma unroll
        for (int ni = 0; ni < 4; ++ni)
#pragma unroll
            for (int r = 0; r < 4; ++r) {
                float p = __builtin_amdgcn_exp2f(s[ni][r]);
                lsum[r] += p;
                Ps[w * 16 + quad * 4 + r][ni * 16 + ln] = f2bf_hu(p);
            }
    }
    // wave-private Ps rows: same-wave DS ordering suffices
#pragma unroll
    for (int kc = 0; kc < 2; ++kc) {
        bf16x8 pa = *(const bf16x8*)&Ps[w * 16 + ln][kc * 32 + quad * 8];
#pragma unroll
        for (int ni = 0; ni < 4; ++ni) {
            bf16x8 vb = *(const bf16x8*)&Vts[ni * 16 + ln][kc * 32 + quad * 8];
            o[ni] = __builtin_amdgcn_mfma_f32_16x16x32_bf16(pa, vb, o[ni], 0, 0, 0);
        }
    }
}

__global__ __launch_bounds__(256) void flash_mfma(
    const short* __restrict__ kb,
    const short* __restrict__ qvb,
    const short* __restrict__ vTb,
    short* __restrict__ attn2)
{
    __shared__ short Ks[64][72];
    __shared__ short Vts[64][72];
    __shared__ short Ps[64][72];

    const int tid = threadIdx.x;
    const int w = tid >> 6, lane = tid & 63, quad = lane >> 4, ln = lane & 15;
    const int bh = blockIdx.x;              // fastest dim -> XCD clustering
    const int qt = 15 - (int)blockIdx.y;    // long blocks dispatch first
    const int b = bh / H_, h = bh % H_;

    const short* Q  = kb  + (size_t)bh * S_ * P_;
    const short* K  = qvb + (size_t)bh * S_ * P_;
    const short* Vt = vTb + (size_t)bh * P_ * S_;

    bf16x8 qf[2];
    {
        const short* qa = Q + (size_t)(qt * 64 + w * 16 + ln) * P_ + quad * 8;
        qf[0] = *(const bf16x8*)(qa);
        qf[1] = *(const bf16x8*)(qa + 32);
    }

    f32x4 o[4] = {};
    float l[4] = {};

    const int r_st = tid >> 3, c8 = tid & 7;
    uint4 pk[2], pv[2];
#pragma unroll
    for (int i = 0; i < 2; ++i) {
        pk[i] = *(const uint4*)(K + (size_t)(r_st + 32 * i) * P_ + c8 * 8);
        pv[i] = *(const uint4*)(Vt + (size_t)(r_st + 32 * i) * S_ + c8 * 8);
    }

    for (int jt = 0; jt <= qt; ++jt) {
        __syncthreads();                    // prior step's Ks/Vts reads done
#pragma unroll
        for (int i = 0; i < 2; ++i) {
            *(uint4*)&Ks[r_st + 32 * i][c8 * 8]  = pk[i];
            *(uint4*)&Vts[r_st + 32 * i][c8 * 8] = pv[i];
        }
        __syncthreads();
        if (jt < qt) {
            int jn = jt + 1;
#pragma unroll
            for (int i = 0; i < 2; ++i) {
                pk[i] = *(const uint4*)(K + (size_t)(jn * 64 + r_st + 32 * i) * P_ + c8 * 8);
                pv[i] = *(const uint4*)(Vt + (size_t)(r_st + 32 * i) * S_ + jn * 64 + c8 * 8);
            }
        }
        flash_step(qf, jt == qt, w, quad, ln, Ks, Vts, Ps, o, l);
    }

#pragma unroll
    for (int r = 0; r < 4; ++r)
#pragma unroll
        for (int off = 1; off < 16; off <<= 1)
            l[r] += __shfl_xor(l[r], off, 16);

    const size_t HP = H_ * P_;
#pragma unroll
    for (int r = 0; r < 4; ++r) {
        float inv = 1.0f / l[r];
        int gi = qt * 64 + w * 16 + quad * 4 + r;
#pragma unroll
        for (int ni = 0; ni < 4; ++ni)
            attn2[((size_t)b * S_ + gi) * HP + h * P_ + ni * 16 + ln] = f2bf_hu(o[ni][r] * inv);
    }
}

// ---------------------------------------------------------------------------
// Stage 4: out = attn2 @ lifting. 64x128 tiles, grid (128, 6). fp32 out.
// ---------------------------------------------------------------------------
__global__ __launch_bounds__(256) void lift_mfma(
    const short* __restrict__ attn2,
    const short* __restrict__ liftT,
    float* __restrict__ outp)
{
    __shared__ short smem[64 * 72 + 128 * 72];
    short (*As)[72] = (short(*)[72])smem;
    short (*Bs)[72] = (short(*)[72])(smem + 64 * 72);
    const int tid = threadIdx.x;
    const int w = tid >> 6, lane = tid & 63, quad = lane >> 4, ln = lane & 15;
    const int wr = (w >> 1) * 32, wc = (w & 1) * 64;
    const int m0 = blockIdx.x * 64, n0 = blockIdx.y * 128;
    const int r_st = tid >> 3, c8 = tid & 7;

    const short* A  = attn2 + (size_t)m0 * E_;
    const short* Bt = liftT + (size_t)n0 * E_;

    uint4 pa[2], pb[4];
#pragma unroll
    for (int i = 0; i < 2; ++i)
        pa[i] = *(const uint4*)(A + (size_t)(r_st + 32 * i) * E_ + c8 * 8);
#pragma unroll
    for (int i = 0; i < 4; ++i)
        pb[i] = *(const uint4*)(Bt + (size_t)(r_st + 32 * i) * E_ + c8 * 8);

    f32x4 acc[2][4] = {};
    for (int k0 = 0; k0 < E_; k0 += 64) {
        __syncthreads();
#pragma unroll
        for (int i = 0; i < 2; ++i)
            *(uint4*)&As[r_st + 32 * i][c8 * 8] = pa[i];
#pragma unroll
        for (int i = 0; i < 4; ++i)
            *(uint4*)&Bs[r_st + 32 * i][c8 * 8] = pb[i];
        __syncthreads();
        if (k0 + 64 < E_) {
#pragma unroll
            for (int i = 0; i < 2; ++i)
                pa[i] = *(const uint4*)(A + (size_t)(r_st + 32 * i) * E_ + k0 + 64 + c8 * 8);
#pragma unroll
            for (int i = 0; i < 4; ++i)
                pb[i] = *(const uint4*)(Bt + (size_t)(r_st + 32 * i) * E_ + k0 + 64 + c8 * 8);
        }
#pragma unroll
        for (int kc = 0; kc < 2; ++kc) {
            bf16x8 af[2], bfr[4];
#pragma unroll
            for (int mi = 0; mi < 2; ++mi)
                af[mi] = *(const bf16x8*)&As[wr + mi * 16 + ln][kc * 32 + quad * 8];
#pragma unroll
            for (int ni = 0; ni < 4; ++ni)
                bfr[ni] = *(const bf16x8*)&Bs[wc + ni * 16 + ln][kc * 32 + quad * 8];
#pragma unroll
            for (int mi = 0; mi < 2; ++mi)
#pragma unroll
                for (int ni = 0; ni < 4; ++ni)
                    acc[mi][ni] = __builtin_amdgcn_mfma_f32_16x16x32_bf16(
                        af[mi], bfr[ni], acc[mi][ni], 0, 0, 0);
        }
    }

#pragma unroll
    for (int mi = 0; mi < 2; ++mi)
#pragma unroll
        for (int ni = 0; ni < 4; ++ni)
#pragma unroll
            for (int r = 0; r < 4; ++r) {
                int m = m0 + wr + mi * 16 + quad * 4 + r;
                int n = n0 + wc + ni * 16 + ln;
                outp[(size_t)m * E_ + n] = acc[mi][ni][r];
            }
}

extern "C" void kernel_launch(void* const* d_in, const int* in_sizes, int n_in,
                              void* d_out, int out_size, void* d_ws, size_t ws_size,
                              hipStream_t stream) {
    (void)in_sizes; (void)n_in; (void)out_size; (void)ws_size;
    const float* x       = (const float*)d_in[0];
    const float* kproj   = (const float*)d_in[1];
    const float* vproj   = (const float*)d_in[2];
    const float* qheads  = (const float*)d_in[3];
    const float* lifting = (const float*)d_in[4];
    float* out = (float*)d_out;

    short* ws = (short*)d_ws;
    const size_t N_W  = (size_t)H_ * P_ * E_;
    const size_t N_L  = (size_t)E_ * E_;
    const size_t N_KV = (size_t)B_ * H_ * S_ * P_;

    short* kTw   = ws;  ws += N_W;
    short* vTw   = ws;  ws += N_W;
    short* liftT = ws;  ws += N_L;
    short* kb    = ws;  ws += N_KV;
    short* vTb   = ws;  ws += N_KV;
    short* qvb   = ws;  ws += N_KV;
    short* attn2 = ws;  ws += N_KV;

    conv_T_kernel<<<dim3(E_ / 64, P_ / 64, H_), 256, 0, stream>>>(kproj, kTw, E_, P_);
    conv_T_kernel<<<dim3(E_ / 64, P_ / 64, H_), 256, 0, stream>>>(vproj, vTw, E_, P_);
    conv_T_kernel<<<dim3(E_ / 64, E_ / 64, 1), 256, 0, stream>>>(lifting, liftT, E_, E_);

    proj_mfma<<<dim3((B_ * S_) / 128, E_ / 128, 2), 256, 0, stream>>>(x, kTw, vTw, kb, vTb);
    qv_mfma<<<dim3(S_ / 128, H_, B_), 256, 0, stream>>>(qheads, vTb, qvb);
    flash_mfma<<<dim3(B_ * H_, 16), 256, 0, stream>>>(kb, qvb, vTb, attn2);
    lift_mfma<<<dim3((B_ * S_) / 64, E_ / 128), 256, 0, stream>>>(attn2, liftT, out);
}